// Round 2
// baseline (15.202 us; speedup 1.0000x reference)
//
#include <hip/hip_runtime.h>

#define NBATCH 512
#define OUT_U 32
#define OUT_V 128
#define NC 16
#define THREADS 256

// 2 blocks per batch; each block computes 16 u-rows x 128 v = 2048 points.
// Phase 1: separable u-contraction into LDS D[16][16] (float4).
// Phase 2: each thread does 8 points (2 chunks x 4 consecutive v), 4 LDS
//          float4 reads per point, vectorized float4 stores.
__global__ __launch_bounds__(THREADS) void surf_eval_kernel(
    const float* __restrict__ ctrl,   // [512][16][16][4]
    const float* __restrict__ Nu,     // [32][4]
    const float* __restrict__ Nv,     // [128][4]
    const int*   __restrict__ uspan,  // [32]
    const int*   __restrict__ vspan,  // [128]
    float*       __restrict__ out)    // [512][32][128][3]
{
    __shared__ float4 sD[16 * NC];     // 4 KB  u-contracted control rows
    __shared__ float  sNv[OUT_V][4];   // 2 KB
    __shared__ int    sVs[OUT_V];      // 512 B

    const int b    = blockIdx.x >> 1;
    const int half = blockIdx.x & 1;   // which 16 u-rows
    const int t    = threadIdx.x;

    if (t < OUT_V) {
        sVs[t] = vspan[t] - 3;
        reinterpret_cast<float4*>(&sNv[0][0])[t] =
            reinterpret_cast<const float4*>(Nv)[t];
    }

    // ---- Phase 1: D[u_local][col] = sum_i Nu[u][i] * ctrl[b][us+i][col]
    {
        const int u_local = t >> 4;          // 0..15
        const int col     = t & 15;          // 0..15
        const int u       = half * 16 + u_local;
        const int us      = uspan[u] - 3;    // 0..12
        const float4 nu   = reinterpret_cast<const float4*>(Nu)[u];

        const float4* cp = reinterpret_cast<const float4*>(ctrl) + (size_t)b * (NC * NC);
        const float4 c0 = cp[(us + 0) * NC + col];
        const float4 c1 = cp[(us + 1) * NC + col];
        const float4 c2 = cp[(us + 2) * NC + col];
        const float4 c3 = cp[(us + 3) * NC + col];

        float4 d;
        d.x = fmaf(nu.x, c0.x, fmaf(nu.y, c1.x, fmaf(nu.z, c2.x, nu.w * c3.x)));
        d.y = fmaf(nu.x, c0.y, fmaf(nu.y, c1.y, fmaf(nu.z, c2.y, nu.w * c3.y)));
        d.z = fmaf(nu.x, c0.z, fmaf(nu.y, c1.z, fmaf(nu.z, c2.z, nu.w * c3.z)));
        d.w = fmaf(nu.x, c0.w, fmaf(nu.y, c1.w, fmaf(nu.z, c2.w, nu.w * c3.w)));
        sD[t] = d;
    }
    __syncthreads();

    // ---- Phase 2: 2 chunks of 1024 points; thread -> 4 consecutive v points
    #pragma unroll
    for (int c = 0; c < 2; ++c) {
        const int pid = c * 1024 + t * 4;    // 0..2047
        const int ul  = pid >> 7;            // 0..15 (u_local)
        const int v0  = pid & 127;           // multiple of 4
        const int uu  = half * 16 + ul;

        const float4* Du = &sD[ul * NC];

        float r[12];
        #pragma unroll
        for (int p = 0; p < 4; ++p) {
            const int v  = v0 + p;
            const int vs = sVs[v];
            const float w0 = sNv[v][0], w1 = sNv[v][1], w2 = sNv[v][2], w3 = sNv[v][3];

            const float4 d0 = Du[vs + 0];
            const float4 d1 = Du[vs + 1];
            const float4 d2 = Du[vs + 2];
            const float4 d3 = Du[vs + 3];

            const float ax = fmaf(w0, d0.x, fmaf(w1, d1.x, fmaf(w2, d2.x, w3 * d3.x)));
            const float ay = fmaf(w0, d0.y, fmaf(w1, d1.y, fmaf(w2, d2.y, w3 * d3.y)));
            const float az = fmaf(w0, d0.z, fmaf(w1, d1.z, fmaf(w2, d2.z, w3 * d3.z)));
            const float aw = fmaf(w0, d0.w, fmaf(w1, d1.w, fmaf(w2, d2.w, w3 * d3.w)));

            const float inv = __builtin_amdgcn_rcpf(fmaxf(aw, 1e-8f));
            r[p * 3 + 0] = ax * inv;
            r[p * 3 + 1] = ay * inv;
            r[p * 3 + 2] = az * inv;
        }

        float4* po = reinterpret_cast<float4*>(
            out + ((size_t)(b * OUT_U + uu) * OUT_V + v0) * 3);
        po[0] = make_float4(r[0], r[1], r[2],  r[3]);
        po[1] = make_float4(r[4], r[5], r[6],  r[7]);
        po[2] = make_float4(r[8], r[9], r[10], r[11]);
    }
}

extern "C" void kernel_launch(void* const* d_in, const int* in_sizes, int n_in,
                              void* d_out, int out_size, void* d_ws, size_t ws_size,
                              hipStream_t stream) {
    const float* ctrl  = (const float*)d_in[0];
    const float* Nu    = (const float*)d_in[1];
    const float* Nv    = (const float*)d_in[2];
    const int*   uspan = (const int*)d_in[3];
    const int*   vspan = (const int*)d_in[4];
    float* out = (float*)d_out;

    dim3 grid(NBATCH * 2);   // 1024 blocks
    dim3 block(THREADS);
    hipLaunchKernelGGL(surf_eval_kernel, grid, block, 0, stream,
                       ctrl, Nu, Nv, uspan, vspan, out);
}

// Round 4
// 15.053 us; speedup vs baseline: 1.0099x; 1.0099x over previous
//
#include <hip/hip_runtime.h>

#define NBATCH 512
#define OUT_U 32
#define OUT_V 128
#define NC 16
#define THREADS 256

typedef float fx4 __attribute__((ext_vector_type(4)));

// 4 blocks per batch; each block: 8 u-rows x 128 v = 1024 points, 1 point-group
// (4 consecutive v) per thread. Phase 1: u-contraction D[8][16] (float4) into
// LDS. Phase 2: 4 ds_read_b128 + weights per 4 points, nontemporal stores.
__global__ __launch_bounds__(THREADS) void surf_eval_kernel(
    const float* __restrict__ ctrl,   // [512][16][16][4]
    const float* __restrict__ Nu,     // [32][4]
    const float* __restrict__ Nv,     // [128][4]
    const int*   __restrict__ uspan,  // [32]
    const int*   __restrict__ vspan,  // [128]
    float*       __restrict__ out)    // [512][32][128][3]
{
    __shared__ float4 sD[8 * NC];      // 2 KB u-contracted rows
    __shared__ float4 sNv[OUT_V];      // 2 KB
    __shared__ int    sVs[OUT_V];      // 512 B

    const int b = blockIdx.x >> 2;
    const int q = blockIdx.x & 3;      // which 8 u-rows
    const int t = threadIdx.x;

    if (t < OUT_V) {
        sVs[t] = vspan[t] - 3;
        sNv[t] = reinterpret_cast<const float4*>(Nv)[t];
    }

    // ---- Phase 1: D[ul][col] = sum_i Nu[u][i] * ctrl[b][us+i][col]
    if (t < 8 * NC) {
        const int ul  = t >> 4;            // 0..7
        const int col = t & 15;            // 0..15
        const int u   = q * 8 + ul;
        const int us  = uspan[u] - 3;      // 0..12
        const float4 nu = reinterpret_cast<const float4*>(Nu)[u];

        const float4* cp = reinterpret_cast<const float4*>(ctrl) + (size_t)b * (NC * NC);
        const float4 c0 = cp[(us + 0) * NC + col];
        const float4 c1 = cp[(us + 1) * NC + col];
        const float4 c2 = cp[(us + 2) * NC + col];
        const float4 c3 = cp[(us + 3) * NC + col];

        float4 d;
        d.x = fmaf(nu.x, c0.x, fmaf(nu.y, c1.x, fmaf(nu.z, c2.x, nu.w * c3.x)));
        d.y = fmaf(nu.x, c0.y, fmaf(nu.y, c1.y, fmaf(nu.z, c2.y, nu.w * c3.y)));
        d.z = fmaf(nu.x, c0.z, fmaf(nu.y, c1.z, fmaf(nu.z, c2.z, nu.w * c3.z)));
        d.w = fmaf(nu.x, c0.w, fmaf(nu.y, c1.w, fmaf(nu.z, c2.w, nu.w * c3.w)));
        sD[t] = d;
    }
    __syncthreads();

    // ---- Phase 2: one group of 4 consecutive v per thread
    const int ul = t >> 5;               // 0..7
    const int v0 = (t & 31) * 4;         // 0..124
    const int u  = q * 8 + ul;
    const float4* Du = &sD[ul * NC];

    float r[12];
    #pragma unroll
    for (int p = 0; p < 4; ++p) {
        const int v  = v0 + p;
        const int vs = sVs[v];
        const float4 w = sNv[v];

        const float4 d0 = Du[vs + 0];
        const float4 d1 = Du[vs + 1];
        const float4 d2 = Du[vs + 2];
        const float4 d3 = Du[vs + 3];

        const float ax = fmaf(w.x, d0.x, fmaf(w.y, d1.x, fmaf(w.z, d2.x, w.w * d3.x)));
        const float ay = fmaf(w.x, d0.y, fmaf(w.y, d1.y, fmaf(w.z, d2.y, w.w * d3.y)));
        const float az = fmaf(w.x, d0.z, fmaf(w.y, d1.z, fmaf(w.z, d2.z, w.w * d3.z)));
        const float aw = fmaf(w.x, d0.w, fmaf(w.y, d1.w, fmaf(w.z, d2.w, w.w * d3.w)));

        const float inv = __builtin_amdgcn_rcpf(fmaxf(aw, 1e-8f));
        r[p * 3 + 0] = ax * inv;
        r[p * 3 + 1] = ay * inv;
        r[p * 3 + 2] = az * inv;
    }

    fx4* po = reinterpret_cast<fx4*>(
        out + ((size_t)(b * OUT_U + u) * OUT_V + v0) * 3);
    fx4 s0 = {r[0], r[1], r[2],  r[3]};
    fx4 s1 = {r[4], r[5], r[6],  r[7]};
    fx4 s2 = {r[8], r[9], r[10], r[11]};
    __builtin_nontemporal_store(s0, po + 0);
    __builtin_nontemporal_store(s1, po + 1);
    __builtin_nontemporal_store(s2, po + 2);
}

extern "C" void kernel_launch(void* const* d_in, const int* in_sizes, int n_in,
                              void* d_out, int out_size, void* d_ws, size_t ws_size,
                              hipStream_t stream) {
    const float* ctrl  = (const float*)d_in[0];
    const float* Nu    = (const float*)d_in[1];
    const float* Nv    = (const float*)d_in[2];
    const int*   uspan = (const int*)d_in[3];
    const int*   vspan = (const int*)d_in[4];
    float* out = (float*)d_out;

    dim3 grid(NBATCH * 4);   // 2048 blocks
    dim3 block(THREADS);
    hipLaunchKernelGGL(surf_eval_kernel, grid, block, 0, stream,
                       ctrl, Nu, Nv, uspan, vspan, out);
}